// Round 2
// 138.278 us; speedup vs baseline: 1.0622x; 1.0622x over previous
//
#include <hip/hip_runtime.h>
#include <hip/hip_fp16.h>

#define BB    32
#define CIN   256
#define COUT  256
#define HH    28
#define WW    28
#define NPIX  784
#define HP    30
#define WP    30

#define BM    64
#define BN    128
#define NT    6               // 6 N-tiles: nt 0..4 = 128 px, nt 5 = 144 px

// workspace:
//   wgen2: fragment-ordered filters (16x16x32 MFMA), per (b,mtH) slice
//          294912 f16. Chunk (8 f16): (c32*9+khw)*512 + sub*64 + quad*16 + col
//          holds A[m = mtH*128 + sub*16 + col][ch = c32*32 + quad*8 .. +7]
//   xpad : [b][30][30][256] f16 zero-padded NHWC
#define SLICE_ELEMS 294912                       // 128 * 2304
#define WGEN_ELEMS  ((size_t)BB * 2 * SLICE_ELEMS)
#define XPAD_OFF    (WGEN_ELEMS)

#define PREP_GENW  512        // (og 0..31) x (c32 0..7) x (bh 0..1)
#define PREP_GENX  960
#define PREP_GRID  (PREP_GENW + PREP_GENX)

typedef _Float16 f16x8 __attribute__((ext_vector_type(8)));
typedef float    f32x4 __attribute__((ext_vector_type(4)));

static __device__ __forceinline__ ushort f2h_bits(float v) {
    __half h = __float2half(v);
    return *reinterpret_cast<ushort*>(&h);
}

static __device__ __forceinline__ void gll16(const ushort* g, ushort* l) {
    __builtin_amdgcn_global_load_lds(
        (const __attribute__((address_space(1))) unsigned int*)g,
        (__attribute__((address_space(3))) unsigned int*)l, 16, 0, 0);
}

#define KOFF(k) (((k) / 3) * 30 + ((k) % 3))

// ---------------------------------------------------------------------------
// Fused prep kernel (unchanged).
// ---------------------------------------------------------------------------
__global__ __launch_bounds__(256) void prep(const float* __restrict__ weight,
                                            const float* __restrict__ se,
                                            const float* __restrict__ x,
                                            ushort* __restrict__ wgen2,
                                            ushort* __restrict__ xpad) {
    __shared__ __align__(16) char smem[29696];
    const int bid = blockIdx.x;
    const int tid = threadIdx.x;

    if (bid < PREP_GENW) {
        // ---- gen_w V5 ----
        const int og  = bid >> 4;
        const int bh  = (bid >> 3) & 1;
        const int c32 = bid & 7;
        const int ol  = tid >> 5;
        const int cl  = tid & 31;
        const int o   = og * 8 + ol;
        const int c   = c32 * 32 + cl;
        const int mtH = og >> 4;

        float*  se_sh = (float*)smem;                  // 1024 B
        ushort* w_lds = (ushort*)(smem + 1024);        // 2 x 2880 ushort

        se_sh[tid] = se[tid];

        float4 wr[18];
        const float4* wp = (const float4*)(weight + ((size_t)o * CIN + c) * 72);
#pragma unroll
        for (int i = 0; i < 18; ++i) wr[i] = wp[i];

        const int khw0 = tid >> 5;
        const int r0   = tid & 31;
        const int q0   = r0 >> 3;
        const int ol0  = r0 & 7;
        const int o0   = og * 8 + ol0;
        const int sub0 = (o0 >> 4) & 7, col0 = o0 & 15;
        const int dst0 = ((c32 * 9 + khw0) * 512 + sub0 * 64 + q0 * 16 + col0) * 8;
        const int src0 = (khw0 * 8 + ol0) * 40 + q0 * 8;
        const int q1   = tid >> 3;
        const int ol1  = tid & 7;
        const int o1   = og * 8 + ol1;
        const int sub1 = (o1 >> 4) & 7, col1 = o1 & 15;
        const int dst1 = ((c32 * 9 + 8) * 512 + sub1 * 64 + q1 * 16 + col1) * 8;
        const int src1 = (8 * 8 + ol1) * 40 + q1 * 8;

        __syncthreads();

        for (int bi = 0; bi < 16; ++bi) {
            const int b   = bh * 16 + bi;
            const int buf = (bi & 1) * 2880;
            const float s0 = se_sh[b * 8 + 0], s1 = se_sh[b * 8 + 1];
            const float s2 = se_sh[b * 8 + 2], s3 = se_sh[b * 8 + 3];
            const float s4 = se_sh[b * 8 + 4], s5 = se_sh[b * 8 + 5];
            const float s6 = se_sh[b * 8 + 6], s7 = se_sh[b * 8 + 7];
#pragma unroll
            for (int k = 0; k < 9; ++k) {
                const float4 w0 = wr[2 * k + 0];
                const float4 w1 = wr[2 * k + 1];
                const float v = w0.x * s0 + w0.y * s1 + w0.z * s2 + w0.w * s3
                              + w1.x * s4 + w1.y * s5 + w1.z * s6 + w1.w * s7;
                w_lds[buf + (k * 8 + ol) * 40 + cl] = f2h_bits(v);
            }
            __syncthreads();
            ushort* slice_base = wgen2 + (size_t)(b * 2 + mtH) * SLICE_ELEMS;
            *(uint4*)(slice_base + dst0) = *(const uint4*)(w_lds + buf + src0);
            if (tid < 32)
                *(uint4*)(slice_base + dst1) = *(const uint4*)(w_lds + buf + src1);
        }
    } else {
        // ---- gen_x ----
        const int idx = bid - PREP_GENW;
        const int hp  = idx % HP;
        const int b   = idx / HP;
        ushort* row = xpad + ((size_t)b * HP + hp) * WP * CIN;

        if (hp == 0 || hp == HP - 1) {
            uint* r32 = (uint*)row;
            for (int i = tid; i < (WP * CIN) / 2; i += 256) r32[i] = 0u;
            return;
        }
        {
            uint* c0 = (uint*)row;
            uint* c1 = (uint*)(row + (WP - 1) * CIN);
            if (tid < 128)       c0[tid] = 0u;
            else                 c1[tid - 128] = 0u;
        }
        float* lds = (float*)smem;
        const int h = hp - 1;
        const float* xr = x + (size_t)b * CIN * NPIX + h * WW;

        for (int f = tid; f < CIN * WW; f += 256) {
            const int cc = f / WW;
            const int w  = f % WW;
            lds[cc * (WW + 1) + w] = xr[(size_t)cc * NPIX + w];
        }
        __syncthreads();
        for (int g2 = tid; g2 < WW * CIN; g2 += 256) {
            const int w  = g2 >> 8;
            const int cc = g2 & 255;
            row[(w + 1) * CIN + cc] = f2h_bits(lds[cc * (WW + 1) + w]);
        }
    }
}

// ---------------------------------------------------------------------------
// dconv tile body, templated on NFR (n-fragments per wave); pixel base `no`
// is runtime. NFR is BLOCK-UNIFORM (all 4 waves of a block instantiate the
// same template) so __syncthreads() is never reached under wave-divergent
// control flow. Out-of-range fragments (nt=5, wn=1, j=4) are clamped for
// addressing and masked at the store.
// Rings: A global->VGPR (3 slots, dist 2); bf LDS->VGPR (3 slots, dist 2);
// Psh dbuf, 1 barrier per c32. sched_group_barrier pins the per-khw pipeline
// (VMEM issue-early -> DS -> MFMA) so LLVM cannot sink the prefetches to
// their uses (baseline VGPR_Count=56 proved the rings were collapsed).
// Psh is qc-XOR swizzled (write side pre-swizzles the gll16 GLOBAL source,
// LDS dest stays lane-linear; read side applies the same XOR) to break the
// quad-stride 4-way bank conflict.
// ---------------------------------------------------------------------------
template<int NFR>
static __device__ __forceinline__ void conv_tile(
    const ushort* __restrict__ wgen2, const ushort* __restrict__ xpad,
    const float* __restrict__ bias, float* __restrict__ out,
    ushort (*Psh)[7680], int b, int mtH, int mtl, int nt, int no, int tid)
{
    const int lane = tid & 63;
    const int wave = tid >> 6;
    const int wm   = wave >> 1;
    const int col  = lane & 15;
    const int quad = lane >> 4;
    const int qb   = quad * 240;     // f16x8-granular base per quad
    const int qx   = quad << 1;      // bank-deskew XOR (0,2,4,6)

    const int mo   = mtH * 128 + mtl * 64 + wm * 32;
    const int h_lo = (nt * BN) / WW;

    const f16x8* ag = (const f16x8*)(wgen2 + (size_t)(b * 2 + mtH) * SLICE_ELEMS)
                      + (mtl * 4 + wm * 2) * 64 + lane;
    const ushort* xp = xpad + (size_t)b * HP * WP * CIN;

    int p_goff[4], p_loff[4];
    bool p_ok[4];
#pragma unroll
    for (int r = 0; r < 4; ++r) {
        const int j = r * 256 + tid;
        p_ok[r] = (j < 960);
        const int jj  = p_ok[r] ? j : 0;
        const int qc  = jj / 240;
        const int em  = jj % 240;
        const int ep  = em ^ (qc << 1);   // inverse swizzle on the GLOBAL source
        const int rr  = ep / 30;
        const int ww  = ep % 30;
        int srow = h_lo + rr;
        if (srow > 29) srow = 29;
        p_goff[r] = (srow * WP + ww) * CIN + qc * 8;
        p_loff[r] = jj * 8;               // LDS dest stays lane-linear (gll16 rule)
    }

    int pixbase[NFR], pst[NFR];
#pragma unroll
    for (int j = 0; j < NFR; ++j) {
        const int p  = no + j * 16 + col;
        pst[j] = p;
        const int pc = p > (NPIX - 1) ? (NPIX - 1) : p;   // clamp masked frags
        pixbase[j] = (pc / WW - h_lo) * 30 + (pc % WW);
    }

    f32x4 acc[2][NFR];
#pragma unroll
    for (int mi = 0; mi < 2; ++mi)
#pragma unroll
        for (int nj = 0; nj < NFR; ++nj)
            acc[mi][nj] = (f32x4){0.f, 0.f, 0.f, 0.f};

    // ---- prologue ----
#pragma unroll
    for (int r = 0; r < 4; ++r)
        if (p_ok[r]) gll16(xp + p_goff[r], &Psh[0][p_loff[r]]);

    f16x8 afr[3][2];
#pragma unroll
    for (int mi = 0; mi < 2; ++mi) afr[0][mi] = ag[mi * 64];
    {
        const f16x8* a1 = ag + (1 << 9);
#pragma unroll
        for (int mi = 0; mi < 2; ++mi) afr[1][mi] = a1[mi * 64];
    }

    f16x8 bfr[3][NFR];

    for (int c32 = 0; c32 < 8; ++c32) {
        __syncthreads();   // patch(c32) resident; prev buffer free

        if (c32 < 7) {
            const int nb = (c32 + 1) & 1;
#pragma unroll
            for (int r = 0; r < 4; ++r)
                if (p_ok[r]) gll16(xp + p_goff[r] + (c32 + 1) * 32,
                                   &Psh[nb][p_loff[r]]);
        }

        const f16x8* Pc = (const f16x8*)Psh[c32 & 1];

        // bf ring prologue: slots 0,1 = khw 0,1
#pragma unroll
        for (int j = 0; j < NFR; ++j) {
            bfr[0][j] = Pc[qb + ((pixbase[j] + KOFF(0)) ^ qx)];
            bfr[1][j] = Pc[qb + ((pixbase[j] + KOFF(1)) ^ qx)];
        }

#pragma unroll
        for (int khw = 0; khw < 9; ++khw) {
            const int st = c32 * 9 + khw;
            // A prefetch, distance 2 (slot khw%3; 9%3==0 keeps ring seamless)
            int sp = st + 2; if (sp > 71) sp = 71;
            const f16x8* apf = ag + ((size_t)sp << 9);
#pragma unroll
            for (int mi = 0; mi < 2; ++mi)
                afr[(khw + 2) % 3][mi] = apf[mi * 64];
            // bf prefetch, distance 2 (within c32)
            if (khw < 7) {
#pragma unroll
                for (int j = 0; j < NFR; ++j)
                    bfr[(khw + 2) % 3][j] =
                        Pc[qb + ((pixbase[j] + KOFF(khw + 2)) ^ qx)];
            }
            // consume
#pragma unroll
            for (int mi = 0; mi < 2; ++mi)
#pragma unroll
                for (int nj = 0; nj < NFR; ++nj)
                    acc[mi][nj] = __builtin_amdgcn_mfma_f32_16x16x32_f16(
                        afr[khw % 3][mi], bfr[khw % 3][nj], acc[mi][nj], 0, 0, 0);
            // pin the pipeline: issue this iteration's prefetches BEFORE the
            // MFMAs so the dist-2 rings survive the machine scheduler.
            __builtin_amdgcn_sched_group_barrier(0x020, 2, 0);        // VMEM_READ
            if (khw < 7)
                __builtin_amdgcn_sched_group_barrier(0x100, NFR, 0);  // DS_READ
            __builtin_amdgcn_sched_group_barrier(0x008, 2 * NFR, 0);  // MFMA
        }
    }

    // ---- epilogue (store-masked for clamped fragments) ----
    float* ob = out + (size_t)b * COUT * NPIX;
#pragma unroll
    for (int mi = 0; mi < 2; ++mi) {
        const int m = mo + mi * 16 + quad * 4;
        const float4 bv = *(const float4*)(bias + m);
#pragma unroll
        for (int nj = 0; nj < NFR; ++nj) {
            const int p = pst[nj];
            if (p < NPIX) {
                ob[(size_t)(m + 0) * NPIX + p] = acc[mi][nj][0] + bv.x;
                ob[(size_t)(m + 1) * NPIX + p] = acc[mi][nj][1] + bv.y;
                ob[(size_t)(m + 2) * NPIX + p] = acc[mi][nj][2] + bv.z;
                ob[(size_t)(m + 3) * NPIX + p] = acc[mi][nj][3] + bv.w;
            }
        }
    }
}

// ---------------------------------------------------------------------------
// dconv: grid 768 = exactly 3 blocks/CU (was 896 = 3.5, uneven + 128 slim
// blocks paying the full A-stream for 1/8 the MFMA work). 49 N-frags per
// (b,mtH,mtl) row-block: nt 0..4 carry 8 frags (wn0/wn1 x 4); nt=5 carries
// 9 valid frags as NFR=5 on BOTH waves (block-uniform template!): wn0 covers
// px 640..719, wn1 covers 720..783 with its j=4 fragment clamped+masked.
// launch_bounds(256,3): 3 resident blocks/CU; regalloc headroom (<=168 VGPR)
// to keep the prefetch rings live.
// ---------------------------------------------------------------------------
__global__ __launch_bounds__(256, 3) void dconv_mfma(const ushort* __restrict__ wgen2,
                                                     const ushort* __restrict__ xpad,
                                                     const float* __restrict__ bias,
                                                     float* __restrict__ out) {
    const int bid    = blockIdx.x;
    const int g      = bid & 7;            // XCD
    const int s      = bid >> 3;           // 0..95
    const int t      = s % 12;
    const int nt     = t % 6;
    const int mtl    = t / 6;
    const int slice2 = g + 8 * (s / 12);   // 0..63 = b*2 + mtH
    const int b      = slice2 >> 1;
    const int mtH    = slice2 & 1;
    const int tid    = threadIdx.x;
    const int wn     = (tid >> 6) & 1;

    __shared__ ushort Psh[2][7680];        // 2 x 15360 B

    if (nt == 5)   // block-uniform branch: all 4 waves take the same template
        conv_tile<5>(wgen2, xpad, bias, out, Psh, b, mtH, mtl, nt, 640 + wn * 80, tid);
    else
        conv_tile<4>(wgen2, xpad, bias, out, Psh, b, mtH, mtl, nt,
                     nt * BN + wn * 64, tid);
}

extern "C" void kernel_launch(void* const* d_in, const int* in_sizes, int n_in,
                              void* d_out, int out_size, void* d_ws, size_t ws_size,
                              hipStream_t stream) {
    const float* x      = (const float*)d_in[0];
    const float* se     = (const float*)d_in[1];
    const float* weight = (const float*)d_in[2];
    const float* bias   = (const float*)d_in[3];
    float* out          = (float*)d_out;

    ushort* wgen2 = (ushort*)d_ws;
    ushort* xpad  = (ushort*)d_ws + XPAD_OFF;
    (void)ws_size; (void)in_sizes; (void)n_in; (void)out_size;

    prep<<<dim3(PREP_GRID), dim3(256), 0, stream>>>(weight, se, x, wgen2, xpad);
    dconv_mfma<<<dim3(BB * 4 * NT), dim3(256), 0, stream>>>(wgen2, xpad, bias, out);
}